// Round 6
// baseline (53.964 us; speedup 1.0000x reference)
//
#include <hip/hip_runtime.h>
#include <hip/hip_bf16.h>

typedef float fx4 __attribute__((ext_vector_type(4)));
typedef short i16x8 __attribute__((ext_vector_type(8)));
typedef unsigned short u16;

#define NEG_INF_F (-9.0e15f)

__device__ inline u16 f2bf(float v){
  __hip_bfloat16 h = __float2bfloat16(v);
  return *reinterpret_cast<u16*>(&h);
}

// ---------------------------------------------------------------------------
// Kernel 1: Wh = x @ W (fp32), f1 = Wh@a1, f2 = Wh@a2 (fp32).
// Wh emitted bf16 in MFMA B-fragment-linear layout whB[bt][kt][ct][lane][8].
// grid (2, 96), 256 threads; thread = one node n.
// ---------------------------------------------------------------------------
__global__ __launch_bounds__(256) void gat_prep(
    const float* __restrict__ input,   // (8,64,12,512)
    const float* __restrict__ W,       // (64,64)
    const float* __restrict__ Avec,    // (128,1)
    u16*   __restrict__ whB,           // (96,16,4,512) bf16 fragment-linear
    float* __restrict__ f1w,           // (96,512)
    float* __restrict__ f2w)           // (96,512)
{
  __shared__ float Wl[64*64];
  __shared__ float Al[128];
  __shared__ u16   Rp[16384];          // 32KB repack buffer
  const int tid = threadIdx.x;
  const int bt  = blockIdx.y;
  const int b   = bt / 12, t = bt % 12;
  const int xb  = blockIdx.x;
  const int n   = xb * 256 + tid;

  {
    const fx4* src = (const fx4*)W;
    fx4* dst = (fx4*)Wl;
    #pragma unroll
    for (int i = 0; i < 4; ++i) dst[tid + 256*i] = src[tid + 256*i];
    if (tid < 32) ((fx4*)Al)[tid] = ((const fx4*)Avec)[tid];
  }
  __syncthreads();

  const float* xp = input + ((size_t)b*64*12 + t) * 512 + n;

  fx4 acc[16];
  #pragma unroll
  for (int i = 0; i < 16; ++i) acc[i] = (fx4){0.f,0.f,0.f,0.f};

  #pragma unroll 8
  for (int f = 0; f < 64; ++f) {
    float xv = xp[(size_t)f * 6144];
    const fx4* wr = (const fx4*)(Wl + f*64);
    #pragma unroll
    for (int o4 = 0; o4 < 16; ++o4) acc[o4] += xv * wr[o4];
  }

  float s1 = 0.f, s2 = 0.f;
  #pragma unroll
  for (int o4 = 0; o4 < 16; ++o4) {
    fx4 v  = acc[o4];
    fx4 w1 = ((const fx4*)Al)[o4];
    fx4 w2 = ((const fx4*)Al)[o4 + 16];
    s1 += v[0]*w1[0] + v[1]*w1[1] + v[2]*w1[2] + v[3]*w1[3];
    s2 += v[0]*w2[0] + v[1]*w2[1] + v[2]*w2[2] + v[3]*w2[3];
  }
  f1w[bt*512 + n] = s1;
  f2w[bt*512 + n] = s2;

  const int ktl  = (n >> 5) & 7;
  const int q    = (n >> 3) & 3;
  const int e    = n & 7;
  const int rowb = ktl*2048 + q*128 + e;
  #pragma unroll
  for (int o4 = 0; o4 < 16; ++o4) {
    #pragma unroll
    for (int c = 0; c < 4; ++c) {
      const int o = o4*4 + c;
      Rp[rowb + (o >> 4)*512 + (o & 15)*8] = f2bf(acc[o4][c]);
    }
  }
  __syncthreads();

  uint4* dst = (uint4*)(whB + ((size_t)bt*16 + xb*8) * 2048);
  const uint4* src = (const uint4*)Rp;
  #pragma unroll
  for (int i = 0; i < 8; ++i) dst[tid + 256*i] = src[tid + 256*i];
}

// ---------------------------------------------------------------------------
// Kernel 2: 2-tile pipelined {masked softmax -> MFMA PV -> ELU}.
// 1D grid 1536 (XCD-chunk swizzled), 256 threads (4 waves).
// Block = 32 rows as two 16-row tiles; tile1 adj loads issued BEFORE tile0's
// MFMA phase so the memory pipe stays busy during compute (T14 pattern).
// Softmax: rank-2 factorization (R5, exact w/ per-row max + slow-path guard),
// deferred normalization past the linear MFMA.
// ---------------------------------------------------------------------------
__global__ __launch_bounds__(256, 4) void gat_attn(
    const int*   __restrict__ adj,   // (96,512,512)
    const u16*   __restrict__ whB,   // (96,16,4,512) bf16 fragment-linear
    const float* __restrict__ f1w,
    const float* __restrict__ f2w,
    float*       __restrict__ out)   // (96,512,64)
{
  __shared__ float f2l[512];
  __shared__ float f1l[32];
  __shared__ float wmaxl[4];
  __shared__ float sums[2][16];
  __shared__ u16   attnl[16*512];    // one tile of unnormalized p (swizzled)

  const int tid = threadIdx.x;
  const int l   = tid & 63;
  const int w   = tid >> 6;

  // bijective XCD-chunk swizzle: same-bt blocks land on the same XCD
  const int id  = blockIdx.x;
  const int sid = (id & 7) * 192 + (id >> 3);   // 1536 = 8 * 192
  const int bt  = sid >> 4;
  const int it  = sid & 15;

  const int4* adj4 = (const int4*)(adj + (size_t)bt*512*512);

  // ---- issue tile0 adj loads immediately (overlap the whole prologue) ----
  const int grow0 = it*32 + w*4;
  int4 p0[4][2];
  #pragma unroll
  for (int r = 0; r < 4; ++r) {
    const int4* ar = adj4 + (size_t)(grow0 + r) * 128;
    p0[r][0] = ar[l];
    p0[r][1] = ar[64 + l];
  }
  __builtin_amdgcn_sched_barrier(0);

  // ---- prologue: stage f2 (+max), f1; build factor tables ----------------
  float2 fv = ((const float2*)(f2w + bt*512))[tid];
  ((float2*)f2l)[tid] = fv;
  float m2 = fmaxf(fv.x, fv.y);
  #pragma unroll
  for (int off = 32; off >= 1; off >>= 1) m2 = fmaxf(m2, __shfl_xor(m2, off));
  if (l == 0) wmaxl[w] = m2;
  if (tid < 32) f1l[tid] = f1w[bt*512 + it*32 + tid];
  __syncthreads();
  const float F2max = fmaxf(fmaxf(wmaxl[0], wmaxl[1]), fmaxf(wmaxl[2], wmaxl[3]));

  const fx4 f20 = ((const fx4*)f2l)[l];
  const fx4 f21 = ((const fx4*)f2l)[64 + l];
  fx4 v0, v1, vh0, vh1;
  #pragma unroll
  for (int c = 0; c < 4; ++c) {
    v0[c]  = __expf(f20[c] - F2max);
    v1[c]  = __expf(f21[c] - F2max);
    vh0[c] = __expf(0.2f*(f20[c] - F2max));
    vh1[c] = __expf(0.2f*(f21[c] - F2max));
  }

  // ---- phase A body (consumes pre[4][2] for 4 rows; writes attnl+ssum) ---
#define PHASE_A(pre, tId)                                                    \
  {                                                                          \
    float ssum[4];                                                           \
    _Pragma("unroll")                                                        \
    for (int r = 0; r < 4; ++r) {                                            \
      const int4 c0 = pre[r][0];                                             \
      const int4 c1 = pre[r][1];                                             \
      const float f1v = f1l[(tId)*16 + w*4 + r];                             \
      float mx = NEG_INF_F;                                                  \
      mx = fmaxf(mx, (c0.x > 0) ? f20[0] : NEG_INF_F);                       \
      mx = fmaxf(mx, (c0.y > 0) ? f20[1] : NEG_INF_F);                       \
      mx = fmaxf(mx, (c0.z > 0) ? f20[2] : NEG_INF_F);                       \
      mx = fmaxf(mx, (c0.w > 0) ? f20[3] : NEG_INF_F);                       \
      mx = fmaxf(mx, (c1.x > 0) ? f21[0] : NEG_INF_F);                       \
      mx = fmaxf(mx, (c1.y > 0) ? f21[1] : NEG_INF_F);                       \
      mx = fmaxf(mx, (c1.z > 0) ? f21[2] : NEG_INF_F);                       \
      mx = fmaxf(mx, (c1.w > 0) ? f21[3] : NEG_INF_F);                       \
      _Pragma("unroll")                                                      \
      for (int off = 32; off >= 1; off >>= 1)                                \
        mx = fmaxf(mx, __shfl_xor(mx, off));                                 \
      const float tM = f1v + mx;                                             \
      const float M  = fmaxf(tM, 0.2f*tM);                                   \
      const float gap = F2max - mx;                                          \
      float sum = 0.f;                                                       \
      ushort4 pk0, pk1;                                                      \
      if (gap <= 80.f) {                                                     \
        const float u   = __expf(f1v + F2max - M);                           \
        const float uh  = __expf(0.2f*(f1v + F2max) - M);                    \
        const float thr = -f1v;                                              \
        float pv;                                                            \
        GAT_F(pk0.x, c0.x, f20[0], v0[0], vh0[0])                            \
        GAT_F(pk0.y, c0.y, f20[1], v0[1], vh0[1])                            \
        GAT_F(pk0.z, c0.z, f20[2], v0[2], vh0[2])                            \
        GAT_F(pk0.w, c0.w, f20[3], v0[3], vh0[3])                            \
        GAT_F(pk1.x, c1.x, f21[0], v1[0], vh1[0])                            \
        GAT_F(pk1.y, c1.y, f21[1], v1[1], vh1[1])                            \
        GAT_F(pk1.z, c1.z, f21[2], v1[2], vh1[2])                            \
        GAT_F(pk1.w, c1.w, f21[3], v1[3], vh1[3])                            \
      } else {                                                               \
        const float Mf = (mx == NEG_INF_F) ? NEG_INF_F : M;                  \
        float pv;                                                            \
        GAT_S(pk0.x, c0.x, f20[0]) GAT_S(pk0.y, c0.y, f20[1])                \
        GAT_S(pk0.z, c0.z, f20[2]) GAT_S(pk0.w, c0.w, f20[3])                \
        GAT_S(pk1.x, c1.x, f21[0]) GAT_S(pk1.y, c1.y, f21[1])                \
        GAT_S(pk1.z, c1.z, f21[2]) GAT_S(pk1.w, c1.w, f21[3])                \
      }                                                                      \
      ssum[r] = sum;                                                         \
      const int rowR = w*4 + r;                                              \
      const unsigned swz = (unsigned)((rowR & 7) << 4);                      \
      char* base = (char*)attnl + rowR * 1024;                               \
      *(ushort4*)(base + (((unsigned)(      8*l)) ^ swz)) = pk0;             \
      *(ushort4*)(base + (((unsigned)(512 + 8*l)) ^ swz)) = pk1;             \
    }                                                                        \
    _Pragma("unroll")                                                        \
    for (int r = 0; r < 4; ++r) {                                            \
      _Pragma("unroll")                                                      \
      for (int off = 32; off >= 1; off >>= 1)                                \
        ssum[r] += __shfl_xor(ssum[r], off);                                 \
    }                                                                        \
    if (l == 0) {                                                            \
      _Pragma("unroll")                                                      \
      for (int r = 0; r < 4; ++r) sums[tId][w*4 + r] = ssum[r];              \
    }                                                                        \
  }

#define GAT_F(pkf, cc, ff, vv, vvh) {                                        \
      const bool cpos = (ff) > thr;                                          \
      float a = cpos ? (vv) : (vvh);                                         \
      float bb = cpos ? u : uh;                                              \
      pv = ((cc) > 0) ? a*bb : 0.f; sum += pv; pkf = f2bf(pv); }
#define GAT_S(pkf, cc, ff) { float s = f1v + (ff); float lr = fmaxf(s, 0.2f*s); \
      float ee = ((cc) > 0) ? lr : NEG_INF_F;                                \
      pv = __expf(ee - Mf); sum += pv; pkf = f2bf(pv); }

  // ---- phase B body (16 MFMA over attnl tile; normalize + ELU + store) ---
#define PHASE_B(tId)                                                         \
  {                                                                          \
    const int r = l & 15, q = l >> 4;                                        \
    const unsigned swzB = (unsigned)((r & 7) << 4);                          \
    const char* aBase = (const char*)attnl + r * 1024;                       \
    const u16*  wp    = whB + (size_t)bt*32768 + w*512 + l*8;                \
    fx4 acc = {0,0,0,0};                                                     \
    _Pragma("unroll")                                                        \
    for (int kt = 0; kt < 16; ++kt) {                                        \
      i16x8 af = *(const i16x8*)(aBase + (((unsigned)(kt*64 + q*16)) ^ swzB)); \
      i16x8 bf = *(const i16x8*)(wp + kt*2048);                              \
      acc = __builtin_amdgcn_mfma_f32_16x16x32_bf16(af, bf, acc, 0, 0, 0);   \
    }                                                                        \
    float* op = out + ((size_t)bt*512 + it*32 + (tId)*16) * 64;              \
    _Pragma("unroll")                                                        \
    for (int rr = 0; rr < 4; ++rr) {                                         \
      const float rs = 1.0f / sums[tId][q*4 + rr];                           \
      float v = acc[rr] * rs;                                                \
      v = v > 0.f ? v : expm1f(v);                                           \
      op[(q*4 + rr)*64 + w*16 + r] = v;                                      \
    }                                                                        \
  }

  // ---------------- tile 0 phase A ----------------------------------------
  PHASE_A(p0, 0)

  // ---- issue tile1 adj loads BEFORE tile0's MFMA phase (pipelined) -------
  const int grow1 = it*32 + 16 + w*4;
  int4 p1[4][2];
  #pragma unroll
  for (int r = 0; r < 4; ++r) {
    const int4* ar = adj4 + (size_t)(grow1 + r) * 128;
    p1[r][0] = ar[l];
    p1[r][1] = ar[64 + l];
  }
  __builtin_amdgcn_sched_barrier(0);

  __syncthreads();            // attnl + sums[0] ready
  PHASE_B(0)
  __syncthreads();            // attnl free for tile1

  // ---------------- tile 1 ------------------------------------------------
  PHASE_A(p1, 1)
  __syncthreads();            // attnl + sums[1] ready
  PHASE_B(1)

#undef PHASE_A
#undef PHASE_B
#undef GAT_F
#undef GAT_S
}

// ---------------------------------------------------------------------------
extern "C" void kernel_launch(void* const* d_in, const int* in_sizes, int n_in,
                              void* d_out, int out_size, void* d_ws, size_t ws_size,
                              hipStream_t stream) {
  const float* input = (const float*)d_in[0];   // (8,64,12,512) f32
  const int*   adj   = (const int*)  d_in[1];   // (8,12,512,512) i32
  const float* W     = (const float*)d_in[2];   // (64,64) f32
  const float* Avec  = (const float*)d_in[3];   // (128,1) f32
  float* out = (float*)d_out;

  // workspace layout: whB bf16 (6,291,456 B) | f1 (196,608 B) | f2 (196,608 B)
  char* ws = (char*)d_ws;
  u16*   whB = (u16*)ws;
  float* f1w = (float*)(ws + 6291456);
  float* f2w = (float*)(ws + 6291456 + 196608);

  gat_prep<<<dim3(2, 96), 256, 0, stream>>>(input, W, Avec, whB, f1w, f2w);
  gat_attn<<<1536, 256, 0, stream>>>(adj, whB, f1w, f2w, out);
}